// Round 2
// baseline (346.967 us; speedup 1.0000x reference)
//
#include <hip/hip_runtime.h>

// TropicalMultiHeadAttention — MI355X (gfx950)  Round 9
// B=2, L=1024, D=1024, H=16, dk=64, SCALE=0.125; causal (mask input ignored).
// Outputs: out (2,1024,1024) f32 ++ attn (2,16,1024,1024) f32.
//
// R9 vs R8 (340us; scores 147us latency-bound: 1-pair K reuse + scalar LDS conflicts):
//  * phase 1 re-mapped: thread owns 4 CONSECUTIVE keys (4t..4t+3) held in regs for the
//    whole phase (loaded once); q-loop reads Q via broadcast ds_read_b128 (conflict-free),
//    dot via one ds_read_b64, result via one ds_write_b64 -> per-pair LDS ~2 ops, no
//    per-pair global loads.  MFMA dot phase (0.5) kept from R8.
//  * gemm_qkv -> m97-style 128x128 tile, BK=32, 4x4 acc/wave (16 MFMA/wave-iter)
//  Pipeline: cvt, gemm_qkv, scores_fused, gemm_out (4 launches).

typedef _Float16 f16;
typedef __attribute__((ext_vector_type(2))) _Float16 h2;
typedef __attribute__((ext_vector_type(8))) _Float16 f16x8;
typedef __attribute__((ext_vector_type(4))) float f32x4;

__device__ inline f32x4 mfma_f16(f16x8 a, f16x8 b, f32x4 c) {
    return __builtin_amdgcn_mfma_f32_16x16x32_f16(a, b, c, 0, 0, 0);
}

__device__ inline void async_copy16(const f16* g, f16* l) {
    __builtin_amdgcn_global_load_lds((const __attribute__((address_space(1))) void*)g,
                                     (__attribute__((address_space(3))) void*)l, 16, 0, 0);
}

// ---------------------------------------------------------------- all f32->f16 converts, one kernel
__global__ __launch_bounds__(256) void cvt_all(const float* __restrict__ x,
                                               const float* __restrict__ Wq,
                                               const float* __restrict__ Wk,
                                               const float* __restrict__ Wv,
                                               const float* __restrict__ Wo,
                                               f16* __restrict__ x16,
                                               f16* __restrict__ w16,
                                               f16* __restrict__ wo16) {
    int i = blockIdx.x * 256 + threadIdx.x;  // float4 index, 1572864 total
    const float* s;
    f16* d;
    int off;
    if (i < 524288)       { s = x;  d = x16;             off = i; }
    else if (i < 786432)  { s = Wq; d = w16;             off = i - 524288; }
    else if (i < 1048576) { s = Wk; d = w16 + (1 << 20); off = i - 786432; }
    else if (i < 1310720) { s = Wv; d = w16 + (2 << 20); off = i - 1048576; }
    else                  { s = Wo; d = wo16;            off = i - 1310720; }
    float4 v = *(const float4*)(s + (size_t)off * 4);
    f16 o[4] = {(f16)v.x, (f16)v.y, (f16)v.z, (f16)v.w};
    *(uint2*)(d + (size_t)off * 4) = *(uint2*)o;
}

// ---------------------------------------------------------------- QKV GEMM: 128x128 tile, BK=32
// C(2048x3072 f16) = A(2048x1024) @ B(3072x1024)^T + bias; V col-tiles (n0>=2048) write V^T.
__global__ __launch_bounds__(256) void gemm_qkv(const f16* __restrict__ A,
                                                const f16* __restrict__ B,
                                                f16* __restrict__ C,
                                                const float* __restrict__ b0,
                                                const float* __restrict__ b1,
                                                const float* __restrict__ b2,
                                                f16* __restrict__ vt) {
    __shared__ f16 At[128 * 32];
    __shared__ f16 Bt[128 * 32];
    const int t = threadIdx.x;
    const int m0 = blockIdx.y * 128, n0 = blockIdx.x * 128;
    const int wave = t >> 6, lane = t & 63;
    const int l16 = lane & 15, quad = lane >> 4;
    const int wm = (wave >> 1) * 64, wn = (wave & 1) * 64;
    const int sr = t >> 2, sc = (t & 3) * 8;
    f32x4 acc[4][4] = {};
    for (int k0 = 0; k0 < 1024; k0 += 32) {
        __syncthreads();
#pragma unroll
        for (int i = 0; i < 2; ++i) {
            async_copy16(A + (size_t)(m0 + sr + i * 64) * 1024 + k0 + sc, &At[t * 8 + i * 2048]);
            async_copy16(B + (size_t)(n0 + sr + i * 64) * 1024 + k0 + sc, &Bt[t * 8 + i * 2048]);
        }
        __syncthreads();
        f16x8 af[4], bf[4];
#pragma unroll
        for (int i = 0; i < 4; ++i) {
            af[i] = *(const f16x8*)&At[(wm + i * 16 + l16) * 32 + quad * 8];
            bf[i] = *(const f16x8*)&Bt[(wn + i * 16 + l16) * 32 + quad * 8];
        }
#pragma unroll
        for (int mi = 0; mi < 4; ++mi)
#pragma unroll
            for (int ni = 0; ni < 4; ++ni)
                acc[mi][ni] = mfma_f16(af[mi], bf[ni], acc[mi][ni]);
    }
#pragma unroll
    for (int mi = 0; mi < 4; ++mi) {
#pragma unroll
        for (int ni = 0; ni < 4; ++ni) {
            int gcol = n0 + wn + ni * 16 + l16;
            const float* bp = (gcol < 1024) ? b0 : (gcol < 2048 ? b1 : b2);
            float bias = bp[gcol & 1023];
            if (n0 >= 2048) {
                int hd = gcol - 2048;
                int hh = hd >> 6, dd = hd & 63;
                int k0r = m0 + wm + mi * 16 + quad * 4;  // 4 consecutive k
                int bb = k0r >> 10;
                f16 o4[4];
#pragma unroll
                for (int rg = 0; rg < 4; ++rg) o4[rg] = (f16)(acc[mi][ni][rg] + bias);
                *(uint2*)&vt[((size_t)((bb * 16 + hh) * 64 + dd)) * 1024 + (k0r & 1023)] =
                    *(uint2*)o4;
            } else {
#pragma unroll
                for (int rg = 0; rg < 4; ++rg) {
                    int grow = m0 + wm + mi * 16 + quad * 4 + rg;
                    C[(size_t)grow * 3072 + gcol] = (f16)(acc[mi][ni][rg] + bias);
                }
            }
        }
    }
}

// ---------------------------------------------------------------- 128x64 MFMA GEMM (out projection)
template <bool OUT16>
__global__ __launch_bounds__(256) void gemm128(const f16* __restrict__ A,
                                               const f16* __restrict__ B,
                                               void* __restrict__ Cv,
                                               const float* __restrict__ b0,
                                               int K, int lda, int ldb, int ldc) {
    __shared__ f16 At[128 * 32];
    __shared__ f16 Bt[64 * 32];
    const int t = threadIdx.x;
    const int m0 = blockIdx.y * 128, n0 = blockIdx.x * 64;
    const int wave = t >> 6, lane = t & 63;
    const int l16 = lane & 15, quad = lane >> 4;
    const int wm = (wave >> 1) * 64, wn = (wave & 1) * 32;
    const int sr = t >> 2, sc = (t & 3) * 8;
    f32x4 acc[4][2] = {};
    for (int k0 = 0; k0 < K; k0 += 32) {
        __syncthreads();
#pragma unroll
        for (int i = 0; i < 2; ++i)
            async_copy16(A + (size_t)(m0 + sr + i * 64) * lda + k0 + sc, &At[t * 8 + i * 2048]);
        async_copy16(B + (size_t)(n0 + sr) * ldb + k0 + sc, &Bt[t * 8]);
        __syncthreads();
        f16x8 af[4], bfr[2];
#pragma unroll
        for (int i = 0; i < 4; ++i)
            af[i] = *(const f16x8*)&At[(wm + i * 16 + l16) * 32 + quad * 8];
#pragma unroll
        for (int i = 0; i < 2; ++i)
            bfr[i] = *(const f16x8*)&Bt[(wn + i * 16 + l16) * 32 + quad * 8];
#pragma unroll
        for (int mi = 0; mi < 4; ++mi)
#pragma unroll
            for (int ni = 0; ni < 2; ++ni)
                acc[mi][ni] = mfma_f16(af[mi], bfr[ni], acc[mi][ni]);
    }
#pragma unroll
    for (int mi = 0; mi < 4; ++mi) {
#pragma unroll
        for (int ni = 0; ni < 2; ++ni) {
            int gcol = n0 + wn + ni * 16 + l16;
            float bias = b0[gcol];
#pragma unroll
            for (int rg = 0; rg < 4; ++rg) {
                int grow = m0 + wm + mi * 16 + quad * 4 + rg;
                float v = acc[mi][ni][rg] + bias;
                if (OUT16)
                    ((f16*)Cv)[(size_t)grow * ldc + gcol] = (f16)v;
                else
                    ((float*)Cv)[(size_t)grow * ldc + gcol] = v;
            }
        }
    }
}

// ---------------------------------------------------------------- scores + softmax + attn + PV (fused)
// Phase 0:   Q tile -> LDS; gate (fused).
// Phase 0.5: Ssm[q][k] = f16 dot(Q[q],K[k]) via MFMA (A = K tile: D row=k, col=q).
// Phase 1:   tropical max + mix.  Thread owns keys 4t..4t+3 (K rows in regs, loaded once).
//            q-loop: Q via broadcast ds_read_b128, dots via ds_read_b64, out ds_write_b64.
// Phase 2:   causal softmax; exp in regs; attn (f32) out + normalized P (f16) to Ssm.
// Phase 3:   O = P @ V via MFMA from Ssm + L2-hot vt16.
__global__ __launch_bounds__(256, 2) void scores_fused(const f16* __restrict__ qkv16,
                                                       const f16* __restrict__ vt16,
                                                       const float* __restrict__ x,
                                                       const float* __restrict__ Wg,
                                                       const float* __restrict__ bgv,
                                                       const float* __restrict__ log_temps,
                                                       float* __restrict__ attn,
                                                       f16* __restrict__ oh) {
    __shared__ f16 Qs[16][80];    // stride 80: 16B-aligned rows
    __shared__ f16 Ssm[16][1032]; // stride 1032 (8B-aligned rows)
    __shared__ float gsm[16];
    const int t = threadIdx.x;
    const int qt = 63 - (blockIdx.x >> 5);  // heavy tiles first
    const int bh = blockIdx.x & 31;
    const int b = bh & 1, h = bh >> 1;
    const int q0 = qt << 4;
    const int lane = t & 63, w = t >> 6;
    const int l16 = lane & 15, quad = lane >> 4;
    const int qmax = q0 + 15;

    {   // Q tile -> LDS
        int rr = t >> 4, cc = (t & 15) * 4;
        *(uint2*)&Qs[rr][cc] =
            *(const uint2*)(qkv16 + (size_t)(b * 1024 + q0 + rr) * 3072 + h * 64 + cc);
    }
    {   // gate (fused): row = t>>4, 16 lanes/row
        int row = t >> 4, ch = t & 15;
        const float* xp = x + (size_t)(b * 1024 + q0 + row) * 1024 + ch * 64;
        const float* wp = Wg + (size_t)h * 1024 + ch * 64;
        float acc = 0.f;
#pragma unroll
        for (int j = 0; j < 16; ++j) {
            float4 xv = *(const float4*)(xp + j * 4);
            float4 wv = *(const float4*)(wp + j * 4);
            acc = fmaf(xv.x, wv.x, acc);
            acc = fmaf(xv.y, wv.y, acc);
            acc = fmaf(xv.z, wv.z, acc);
            acc = fmaf(xv.w, wv.w, acc);
        }
#pragma unroll
        for (int o = 8; o > 0; o >>= 1) acc += __shfl_xor(acc, o);
        if (ch == 0) gsm[row] = 1.0f / (1.0f + __expf(-(acc + bgv[h])));
    }
    float tau = __expf(log_temps[h]);
    tau = fminf(fmaxf(tau, 0.02f), 10.0f);
    const float invtau = 1.0f / tau;
    __syncthreads();

    // ---- phase 0.5: dot scores via MFMA -> Ssm (f16). Wave w: key-tiles w, w+4, ...
    {
        f16x8 qf0 = *(const f16x8*)&Qs[l16][quad * 8];
        f16x8 qf1 = *(const f16x8*)&Qs[l16][32 + quad * 8];
        const f16* Kb = qkv16 + (size_t)(b * 1024 + l16) * 3072 + 1024 + h * 64 + quad * 8;
        for (int kb = w * 16; kb <= qmax; kb += 64) {
            f16x8 kf0 = *(const f16x8*)(Kb + (size_t)kb * 3072);
            f16x8 kf1 = *(const f16x8*)(Kb + (size_t)kb * 3072 + 32);
            f32x4 acc = {};
            acc = mfma_f16(kf0, qf0, acc);
            acc = mfma_f16(kf1, qf1, acc);
            f16 o4[4];
#pragma unroll
            for (int rg = 0; rg < 4; ++rg) o4[rg] = (f16)acc[rg];
            *(uint2*)&Ssm[l16][kb + quad * 4] = *(uint2*)o4;  // D: row=k(quad*4+rg), col=q(l16)
        }
    }
    __syncthreads();

    // ---- phase 1: tropical max + mix.  Thread owns keys 4t..4t+3, K rows in regs.
    {
        const int k0 = t * 4;
        if (k0 <= qmax) {
            h2 kr[4][32];
            const f16* Kp = qkv16 + (size_t)(b * 1024 + k0) * 3072 + 1024 + h * 64;
#pragma unroll
            for (int j = 0; j < 4; ++j)
#pragma unroll
                for (int i = 0; i < 8; ++i)
                    *(f16x8*)&kr[j][i * 4] = *(const f16x8*)(Kp + (size_t)j * 3072 + i * 8);
#pragma unroll 2
            for (int q = 0; q < 16; ++q) {
                h2 qr[32];
#pragma unroll
                for (int i = 0; i < 8; ++i)
                    *(f16x8*)&qr[i * 4] = *(const f16x8*)&Qs[q][i * 8];  // broadcast
                const float g = gsm[q];
                f16 d4[4];
                *(uint2*)d4 = *(const uint2*)&Ssm[q][k0];
                f16 o4[4];
#pragma unroll
                for (int j = 0; j < 4; ++j) {
                    h2 ta = qr[0] + kr[j][0], tb = qr[1] + kr[j][1];
#pragma unroll
                    for (int i = 2; i < 32; i += 2) {
                        ta = __builtin_elementwise_max(ta, qr[i] + kr[j][i]);
                        tb = __builtin_elementwise_max(tb, qr[i + 1] + kr[j][i + 1]);
                    }
                    h2 tc = __builtin_elementwise_max(ta, tb);
                    float tm = fmaxf((float)tc[0], (float)tc[1]);
                    o4[j] = (f16)((g * tm + (1.0f - g) * (float)d4[j]) * 0.125f);
                }
                *(uint2*)&Ssm[q][k0] = *(uint2*)o4;
            }
        }
    }
    __syncthreads();

    // ---- phase 2: causal softmax; attn (f32) out + normalized P (f16) back to Ssm
#pragma unroll
    for (int j = 0; j < 4; ++j) {
        int q = w * 4 + j;
        int qg = q0 + q;
        float m = -1e30f;
        for (int k = lane; k <= qg; k += 64) m = fmaxf(m, (float)Ssm[q][k]);
#pragma unroll
        for (int o = 32; o > 0; o >>= 1) m = fmaxf(m, __shfl_xor(m, o));
        float e[16];
        float ssum = 0.f;
#pragma unroll
        for (int i = 0; i < 16; ++i) {
            int k = lane + i * 64;
            if (k <= qg) {
                float v = __expf(((float)Ssm[q][k] - m) * invtau);
                e[i] = v;
                ssum += v;
            } else
                e[i] = 0.f;
        }
#pragma unroll
        for (int o = 32; o > 0; o >>= 1) ssum += __shfl_xor(ssum, o);
        float inv = 1.0f / ssum;
        float* orow = attn + ((size_t)((b * 16 + h) * 1024 + qg) << 10);
#pragma unroll
        for (int i = 0; i < 16; ++i) {
            int k = lane + i * 64;
            float val = e[i] * inv;
            orow[k] = val;
            Ssm[q][k] = (f16)val;  // normalized P (zeros above diag) for PV
        }
    }
    __syncthreads();

    // ---- phase 3: O(16x64) = P(16x1024) @ V(1024x64); wave w owns d-tile [w*16, w*16+16)
    {
        const int dw = w * 16;
        f32x4 acc = {};
        const int nkt = (q0 + 47) >> 5;  // ceil((qmax+1)/32)
        const f16* Vb = vt16 + ((size_t)((b * 16 + h) * 64 + dw + l16)) * 1024 + quad * 8;
#pragma unroll 4
        for (int kt = 0; kt < nkt; ++kt) {
            const int kb = kt << 5;
            f16x8 a = *(const f16x8*)&Ssm[l16][kb + quad * 8];
            f16x8 bf = *(const f16x8*)(Vb + kb);
            acc = mfma_f16(a, bf, acc);
        }
#pragma unroll
        for (int rg = 0; rg < 4; ++rg)
            oh[(size_t)(b * 1024 + q0 + quad * 4 + rg) * 1024 + h * 64 + dw + l16] =
                (f16)acc[rg];
    }
}

// ----------------------------------------------------------------
extern "C" void kernel_launch(void* const* d_in, const int* in_sizes, int n_in,
                              void* d_out, int out_size, void* d_ws, size_t ws_size,
                              hipStream_t stream) {
    const float* x  = (const float*)d_in[0];
    const float* Wq = (const float*)d_in[2];
    const float* bq = (const float*)d_in[3];
    const float* Wk = (const float*)d_in[4];
    const float* bk = (const float*)d_in[5];
    const float* Wv = (const float*)d_in[6];
    const float* bv = (const float*)d_in[7];
    const float* Wo = (const float*)d_in[8];
    const float* bo = (const float*)d_in[9];
    const float* Wg = (const float*)d_in[10];
    const float* bg = (const float*)d_in[11];
    const float* lt = (const float*)d_in[12];
    float* out = (float*)d_out;
    float* attn = out + (size_t)2 * 1024 * 1024;

    char* ws = (char*)d_ws;
    const size_t MB = (size_t)1 << 20;
    f16*   x16   = (f16*)ws;                  // 4 MiB (2048x1024)
    f16*   w16   = (f16*)(ws + 4 * MB);       // 6 MiB (Wq|Wk|Wv 3072x1024)
    f16*   wo16  = (f16*)(ws + 10 * MB);      // 2 MiB
    f16*   qkv16 = (f16*)(ws + 12 * MB);      // 12 MiB (Q,K used; V third unused)
    f16*   vt16  = (f16*)(ws + 24 * MB);      // 4 MiB (V^T per (b*16+h))
    f16*   oh16  = (f16*)(ws + 29 * MB);      // 4 MiB — total 33 MiB

    cvt_all<<<6144, 256, 0, stream>>>(x, Wq, Wk, Wv, Wo, x16, w16, wo16);
    gemm_qkv<<<dim3(24, 16), 256, 0, stream>>>(x16, w16, qkv16, bq, bk, bv, vt16);
    scores_fused<<<2048, 256, 0, stream>>>(qkv16, vt16, x, Wg, bg, lt, attn, oh16);
    gemm128<false><<<dim3(16, 16), 256, 0, stream>>>(oh16, wo16, out, bo, 1024, 1024, 1024, 1024);
}

// Round 3
// 320.617 us; speedup vs baseline: 1.0822x; 1.0822x over previous
//
#include <hip/hip_runtime.h>

// TropicalMultiHeadAttention — MI355X (gfx950)  Round 10
// B=2, L=1024, D=1024, H=16, dk=64, SCALE=0.125; causal (mask input ignored).
// Outputs: out (2,1024,1024) f32 ++ attn (2,16,1024,1024) f32.
//
// R10 = R7 (304us, proven) + surgical changes only:
//  * phase 0.5 (from R8, proven): dot scores via MFMA -> Ssm (f16)
//  * phase 1 = R7's EXACT mapping (2 keys/thread/pass, K in 64 VGPRs for all 16 q's,
//    Q broadcast ds_read) minus dot2acc (-32 VALU/pair); dot read back from Ssm
//    (scalar u16, consecutive lanes = free 2-way)
//  * gate fused (from R8, proven) — saves a launch
//  R9's failure: kr[4][32]=128 VGPR + launch_bounds cap -> compiler rematerialized
//  K loads per-q (FETCH 25MB, VALUBusy 38%, occ 21%). Reverted.
//  Pipeline: cvt, gemm_qkv, scores_fused, gemm_out (4 launches).

typedef _Float16 f16;
typedef __attribute__((ext_vector_type(2))) _Float16 h2;
typedef __attribute__((ext_vector_type(8))) _Float16 f16x8;
typedef __attribute__((ext_vector_type(4))) float f32x4;

__device__ inline f32x4 mfma_f16(f16x8 a, f16x8 b, f32x4 c) {
    return __builtin_amdgcn_mfma_f32_16x16x32_f16(a, b, c, 0, 0, 0);
}

__device__ inline void async_copy16(const f16* g, f16* l) {
    __builtin_amdgcn_global_load_lds((const __attribute__((address_space(1))) void*)g,
                                     (__attribute__((address_space(3))) void*)l, 16, 0, 0);
}

// ---------------------------------------------------------------- all f32->f16 converts, one kernel
__global__ __launch_bounds__(256) void cvt_all(const float* __restrict__ x,
                                               const float* __restrict__ Wq,
                                               const float* __restrict__ Wk,
                                               const float* __restrict__ Wv,
                                               const float* __restrict__ Wo,
                                               f16* __restrict__ x16,
                                               f16* __restrict__ w16,
                                               f16* __restrict__ wo16) {
    int i = blockIdx.x * 256 + threadIdx.x;  // float4 index, 1572864 total
    const float* s;
    f16* d;
    int off;
    if (i < 524288)       { s = x;  d = x16;             off = i; }
    else if (i < 786432)  { s = Wq; d = w16;             off = i - 524288; }
    else if (i < 1048576) { s = Wk; d = w16 + (1 << 20); off = i - 786432; }
    else if (i < 1310720) { s = Wv; d = w16 + (2 << 20); off = i - 1048576; }
    else                  { s = Wo; d = wo16;            off = i - 1310720; }
    float4 v = *(const float4*)(s + (size_t)off * 4);
    f16 o[4] = {(f16)v.x, (f16)v.y, (f16)v.z, (f16)v.w};
    *(uint2*)(d + (size_t)off * 4) = *(uint2*)o;
}

// ---------------------------------------------------------------- 128x64 MFMA GEMM  C = A @ B^T + bias
// R7-proven. VTR: V column-tiles (n0>=2048) write V^T to vt.
template <bool OUT16, bool VTR>
__global__ __launch_bounds__(256) void gemm128(const f16* __restrict__ A,
                                               const f16* __restrict__ B,
                                               void* __restrict__ Cv,
                                               const float* __restrict__ b0,
                                               const float* __restrict__ b1,
                                               const float* __restrict__ b2,
                                               f16* __restrict__ vt,
                                               int K, int lda, int ldb, int ldc) {
    __shared__ f16 At[128 * 32];
    __shared__ f16 Bt[64 * 32];
    const int t = threadIdx.x;
    const int m0 = blockIdx.y * 128, n0 = blockIdx.x * 64;
    const int wave = t >> 6, lane = t & 63;
    const int l16 = lane & 15, quad = lane >> 4;
    const int wm = (wave >> 1) * 64, wn = (wave & 1) * 32;
    const int sr = t >> 2, sc = (t & 3) * 8;
    f32x4 acc[4][2] = {};
    for (int k0 = 0; k0 < K; k0 += 32) {
        __syncthreads();
#pragma unroll
        for (int i = 0; i < 2; ++i)
            async_copy16(A + (size_t)(m0 + sr + i * 64) * lda + k0 + sc, &At[t * 8 + i * 2048]);
        async_copy16(B + (size_t)(n0 + sr) * ldb + k0 + sc, &Bt[t * 8]);
        __syncthreads();
        f16x8 af[4], bfr[2];
#pragma unroll
        for (int i = 0; i < 4; ++i)
            af[i] = *(const f16x8*)&At[(wm + i * 16 + l16) * 32 + quad * 8];
#pragma unroll
        for (int i = 0; i < 2; ++i)
            bfr[i] = *(const f16x8*)&Bt[(wn + i * 16 + l16) * 32 + quad * 8];
#pragma unroll
        for (int mi = 0; mi < 4; ++mi)
#pragma unroll
            for (int ni = 0; ni < 2; ++ni)
                acc[mi][ni] = mfma_f16(af[mi], bfr[ni], acc[mi][ni]);
    }
#pragma unroll
    for (int mi = 0; mi < 4; ++mi) {
#pragma unroll
        for (int ni = 0; ni < 2; ++ni) {
            int gcol = n0 + wn + ni * 16 + l16;
            const float* bp = (gcol < 1024) ? b0 : (gcol < 2048 ? b1 : b2);
            float bias = bp[gcol & 1023];
            if (VTR && n0 >= 2048) {
                int hd = gcol - 2048;
                int h = hd >> 6, d = hd & 63;
                int k0r = m0 + wm + mi * 16 + quad * 4;  // 4 consecutive k
                int b = k0r >> 10;
                f16 o4[4];
#pragma unroll
                for (int rg = 0; rg < 4; ++rg) o4[rg] = (f16)(acc[mi][ni][rg] + bias);
                *(uint2*)&vt[((size_t)((b * 16 + h) * 64 + d)) * 1024 + (k0r & 1023)] =
                    *(uint2*)o4;
            } else {
#pragma unroll
                for (int rg = 0; rg < 4; ++rg) {
                    int grow = m0 + wm + mi * 16 + quad * 4 + rg;
                    float v = acc[mi][ni][rg] + bias;
                    if (OUT16)
                        ((f16*)Cv)[(size_t)grow * ldc + gcol] = (f16)v;
                    else
                        ((float*)Cv)[(size_t)grow * ldc + gcol] = v;
                }
            }
        }
    }
}

// ---------------------------------------------------------------- scores + softmax + attn + PV (fused)
// Phase 0:   Q tile -> LDS; gate (fused).
// Phase 0.5: Ssm[q][k] = f16 dot(Q[q],K[k]) via MFMA (A = K tile: D row=k, col=q).
// Phase 1:   R7 mapping. Thread owns keys {p*512+t, p*512+t+256}; K rows in regs for all
//            16 q's; Q via broadcast ds_read_b128; tropical 64 pk-ops; dot from Ssm; mix.
// Phase 2:   causal softmax; exp cached in regs; attn (f32) out + normalized P (f16) to Ssm.
// Phase 3:   O = P @ V via MFMA from Ssm + L2-hot vt16.
__global__ __launch_bounds__(256) void scores_fused(const f16* __restrict__ qkv16,
                                                    const f16* __restrict__ vt16,
                                                    const float* __restrict__ x,
                                                    const float* __restrict__ Wg,
                                                    const float* __restrict__ bgv,
                                                    const float* __restrict__ log_temps,
                                                    float* __restrict__ attn,
                                                    f16* __restrict__ oh) {
    __shared__ f16 Qs[16][80];    // stride 80: 16B-aligned rows
    __shared__ f16 Ssm[16][1032]; // stride 1032 (8B-aligned rows)
    __shared__ float gsm[16];
    const int t = threadIdx.x;
    const int qt = 63 - (blockIdx.x >> 5);  // heavy tiles first
    const int bh = blockIdx.x & 31;
    const int b = bh & 1, h = bh >> 1;
    const int q0 = qt << 4;
    const int lane = t & 63, w = t >> 6;
    const int l16 = lane & 15, quad = lane >> 4;
    const int qmax = q0 + 15;

    {   // Q tile -> LDS
        int rr = t >> 4, cc = (t & 15) * 4;
        *(uint2*)&Qs[rr][cc] =
            *(const uint2*)(qkv16 + (size_t)(b * 1024 + q0 + rr) * 3072 + h * 64 + cc);
    }
    {   // gate (fused): row = t>>4, 16 lanes/row
        int row = t >> 4, ch = t & 15;
        const float* xp = x + (size_t)(b * 1024 + q0 + row) * 1024 + ch * 64;
        const float* wp = Wg + (size_t)h * 1024 + ch * 64;
        float acc = 0.f;
#pragma unroll
        for (int j = 0; j < 16; ++j) {
            float4 xv = *(const float4*)(xp + j * 4);
            float4 wv = *(const float4*)(wp + j * 4);
            acc = fmaf(xv.x, wv.x, acc);
            acc = fmaf(xv.y, wv.y, acc);
            acc = fmaf(xv.z, wv.z, acc);
            acc = fmaf(xv.w, wv.w, acc);
        }
#pragma unroll
        for (int o = 8; o > 0; o >>= 1) acc += __shfl_xor(acc, o);
        if (ch == 0) gsm[row] = 1.0f / (1.0f + __expf(-(acc + bgv[h])));
    }
    float tau = __expf(log_temps[h]);
    tau = fminf(fmaxf(tau, 0.02f), 10.0f);
    const float invtau = 1.0f / tau;
    __syncthreads();

    // ---- phase 0.5: dot scores via MFMA -> Ssm (f16). Wave w: key-tiles w, w+4, ...
    {
        f16x8 qf0 = *(const f16x8*)&Qs[l16][quad * 8];
        f16x8 qf1 = *(const f16x8*)&Qs[l16][32 + quad * 8];
        const f16* Kb = qkv16 + (size_t)(b * 1024 + l16) * 3072 + 1024 + h * 64 + quad * 8;
        for (int kb = w * 16; kb <= qmax; kb += 64) {
            f16x8 kf0 = *(const f16x8*)(Kb + (size_t)kb * 3072);
            f16x8 kf1 = *(const f16x8*)(Kb + (size_t)kb * 3072 + 32);
            f32x4 acc = {};
            acc = mfma_f16(kf0, qf0, acc);
            acc = mfma_f16(kf1, qf1, acc);
            f16 o4[4];
#pragma unroll
            for (int rg = 0; rg < 4; ++rg) o4[rg] = (f16)acc[rg];
            *(uint2*)&Ssm[l16][kb + quad * 4] = *(uint2*)o4;  // D: row=k(quad*4+rg), col=q(l16)
        }
    }
    __syncthreads();

    // ---- phase 1: tropical max + mix (R7 mapping, dot from Ssm)
    {
        const int npass = (qmax >> 9) + 1;  // 512-key passes
        for (int p = 0; p < npass; ++p) {
            const int k1 = (p << 9) + t;
            const int k2 = k1 + 256;
            const bool a1 = (k1 <= qmax), a2 = (k2 <= qmax);
            if (a1) {
                const f16* Kp1 = qkv16 + (size_t)(b * 1024 + k1) * 3072 + 1024 + h * 64;
                h2 kr1[32], kr2[32];
#pragma unroll
                for (int i = 0; i < 8; ++i) *(f16x8*)&kr1[i * 4] = ((const f16x8*)Kp1)[i];
                if (a2) {
                    const f16* Kp2 = qkv16 + (size_t)(b * 1024 + k2) * 3072 + 1024 + h * 64;
#pragma unroll
                    for (int i = 0; i < 8; ++i) *(f16x8*)&kr2[i * 4] = ((const f16x8*)Kp2)[i];
                }
#pragma unroll 2
                for (int q = 0; q < 16; ++q) {
                    h2 qr[32];
#pragma unroll
                    for (int i = 0; i < 8; ++i)
                        *(f16x8*)&qr[i * 4] = *(const f16x8*)&Qs[q][i * 8];  // broadcast
                    const float g = gsm[q];
                    {
                        float dot = (float)Ssm[q][k1];
                        h2 ta = qr[0] + kr1[0], tb = qr[1] + kr1[1];
#pragma unroll
                        for (int i = 2; i < 32; i += 2) {
                            ta = __builtin_elementwise_max(ta, qr[i] + kr1[i]);
                            tb = __builtin_elementwise_max(tb, qr[i + 1] + kr1[i + 1]);
                        }
                        h2 tc = __builtin_elementwise_max(ta, tb);
                        float tm = fmaxf((float)tc[0], (float)tc[1]);
                        Ssm[q][k1] = (f16)((g * tm + (1.0f - g) * dot) * 0.125f);
                    }
                    if (a2) {
                        float dot = (float)Ssm[q][k2];
                        h2 ta = qr[0] + kr2[0], tb = qr[1] + kr2[1];
#pragma unroll
                        for (int i = 2; i < 32; i += 2) {
                            ta = __builtin_elementwise_max(ta, qr[i] + kr2[i]);
                            tb = __builtin_elementwise_max(tb, qr[i + 1] + kr2[i + 1]);
                        }
                        h2 tc = __builtin_elementwise_max(ta, tb);
                        float tm = fmaxf((float)tc[0], (float)tc[1]);
                        Ssm[q][k2] = (f16)((g * tm + (1.0f - g) * dot) * 0.125f);
                    }
                }
            }
        }
    }
    __syncthreads();

    // ---- phase 2: causal softmax; attn (f32) out + normalized P (f16) back to Ssm
#pragma unroll
    for (int j = 0; j < 4; ++j) {
        int q = w * 4 + j;
        int qg = q0 + q;
        float m = -1e30f;
        for (int k = lane; k <= qg; k += 64) m = fmaxf(m, (float)Ssm[q][k]);
#pragma unroll
        for (int o = 32; o > 0; o >>= 1) m = fmaxf(m, __shfl_xor(m, o));
        float e[16];
        float ssum = 0.f;
#pragma unroll
        for (int i = 0; i < 16; ++i) {
            int k = lane + i * 64;
            if (k <= qg) {
                float v = __expf(((float)Ssm[q][k] - m) * invtau);
                e[i] = v;
                ssum += v;
            } else
                e[i] = 0.f;
        }
#pragma unroll
        for (int o = 32; o > 0; o >>= 1) ssum += __shfl_xor(ssum, o);
        float inv = 1.0f / ssum;
        float* orow = attn + ((size_t)((b * 16 + h) * 1024 + qg) << 10);
#pragma unroll
        for (int i = 0; i < 16; ++i) {
            int k = lane + i * 64;
            float val = e[i] * inv;
            orow[k] = val;
            Ssm[q][k] = (f16)val;  // normalized P (zeros above diag) for PV
        }
    }
    __syncthreads();

    // ---- phase 3: O(16x64) = P(16x1024) @ V(1024x64); wave w owns d-tile [w*16, w*16+16)
    {
        const int dw = w * 16;
        f32x4 acc = {};
        const int nkt = (q0 + 47) >> 5;  // ceil((qmax+1)/32)
        const f16* Vb = vt16 + ((size_t)((b * 16 + h) * 64 + dw + l16)) * 1024 + quad * 8;
#pragma unroll 4
        for (int kt = 0; kt < nkt; ++kt) {
            const int kb = kt << 5;
            f16x8 a = *(const f16x8*)&Ssm[l16][kb + quad * 8];
            f16x8 bf = *(const f16x8*)(Vb + kb);
            acc = mfma_f16(a, bf, acc);
        }
#pragma unroll
        for (int rg = 0; rg < 4; ++rg)
            oh[(size_t)(b * 1024 + q0 + quad * 4 + rg) * 1024 + h * 64 + dw + l16] =
                (f16)acc[rg];
    }
}

// ----------------------------------------------------------------
extern "C" void kernel_launch(void* const* d_in, const int* in_sizes, int n_in,
                              void* d_out, int out_size, void* d_ws, size_t ws_size,
                              hipStream_t stream) {
    const float* x  = (const float*)d_in[0];
    const float* Wq = (const float*)d_in[2];
    const float* bq = (const float*)d_in[3];
    const float* Wk = (const float*)d_in[4];
    const float* bk = (const float*)d_in[5];
    const float* Wv = (const float*)d_in[6];
    const float* bv = (const float*)d_in[7];
    const float* Wo = (const float*)d_in[8];
    const float* bo = (const float*)d_in[9];
    const float* Wg = (const float*)d_in[10];
    const float* bg = (const float*)d_in[11];
    const float* lt = (const float*)d_in[12];
    float* out = (float*)d_out;
    float* attn = out + (size_t)2 * 1024 * 1024;

    char* ws = (char*)d_ws;
    const size_t MB = (size_t)1 << 20;
    f16*   x16   = (f16*)ws;                  // 4 MiB (2048x1024)
    f16*   w16   = (f16*)(ws + 4 * MB);       // 6 MiB (Wq|Wk|Wv 3072x1024)
    f16*   wo16  = (f16*)(ws + 10 * MB);      // 2 MiB
    f16*   qkv16 = (f16*)(ws + 12 * MB);      // 12 MiB (Q,K used; V third unused)
    f16*   vt16  = (f16*)(ws + 24 * MB);      // 4 MiB (V^T per (b*16+h))
    f16*   oh16  = (f16*)(ws + 29 * MB);      // 4 MiB — total 33 MiB

    cvt_all<<<6144, 256, 0, stream>>>(x, Wq, Wk, Wv, Wo, x16, w16, wo16);
    gemm128<true, true><<<dim3(48, 16), 256, 0, stream>>>(x16, w16, qkv16, bq, bk, bv,
                                                          vt16, 1024, 1024, 1024, 3072);
    scores_fused<<<2048, 256, 0, stream>>>(qkv16, vt16, x, Wg, bg, lt, attn, oh16);
    gemm128<false, false><<<dim3(16, 16), 256, 0, stream>>>(oh16, wo16, out, bo, bo, bo,
                                                            nullptr, 1024, 1024, 1024, 1024);
}